// Round 1
// baseline (1499.475 us; speedup 1.0000x reference)
//
#include <hip/hip_runtime.h>
#include <hip/hip_bf16.h>

#define NN 50000
#define NEG_SLOPE 0.2f

// ---- float <-> order-preserving uint encoding (for atomicMax on floats) ----
__device__ __forceinline__ unsigned encf(float x) {
    unsigned u = __float_as_uint(x);
    return (u >> 31) ? ~u : (u | 0x80000000u);
}
__device__ __forceinline__ float decf(unsigned u) {
    return __uint_as_float((u >> 31) ? (u ^ 0x80000000u) : ~u);
}
// encoded -inf: bits(-inf)=0xFF800000 -> ~ = 0x007FFFFF
#define ENC_NEG_INF 0x007FFFFFu

// ---- init accumulators (ws is poisoned 0xAA before every call) ----
__global__ void init_kernel(float* s1, float* agg1, unsigned* m1,
                            float* s2, float* agg2, unsigned* m2, int N) {
    int i = blockIdx.x * blockDim.x + threadIdx.x;
    int st = gridDim.x * blockDim.x;
    for (int j = i; j < N * 128; j += st) agg1[j] = 0.f;
    for (int j = i; j < N * 32; j += st) agg2[j] = 0.f;
    for (int j = i; j < N * 4; j += st) { s1[j] = 0.f; m1[j] = ENC_NEG_INF; }
    for (int j = i; j < N; j += st) { s2[j] = 0.f; m2[j] = ENC_NEG_INF; }
}

// ---- z1 = h @ W1  [N,128]x[128,128], fused el1/er1 (per-head dot with al1/ar1) ----
#define TM 16
__global__ __launch_bounds__(128) void gemm1_kernel(
        const float* __restrict__ h, const float* __restrict__ W1,
        const float* __restrict__ al1, const float* __restrict__ ar1,
        float* __restrict__ z1, float* __restrict__ el1, float* __restrict__ er1) {
    __shared__ float hs[TM][128];
    int tid = threadIdx.x;
    int row0 = blockIdx.x * TM;
    #pragma unroll
    for (int r = 0; r < TM; ++r)
        hs[r][tid] = h[(size_t)(row0 + r) * 128 + tid];
    __syncthreads();
    float acc[TM];
    #pragma unroll
    for (int r = 0; r < TM; ++r) acc[r] = 0.f;
    for (int k = 0; k < 128; ++k) {
        float w = W1[k * 128 + tid];
        #pragma unroll
        for (int r = 0; r < TM; ++r) acc[r] += hs[r][k] * w;
    }
    float a = al1[tid], b = ar1[tid];
    int head = tid >> 5, lane32 = tid & 31;
    #pragma unroll
    for (int r = 0; r < TM; ++r) {
        z1[(size_t)(row0 + r) * 128 + tid] = acc[r];
        float pl = acc[r] * a, pr = acc[r] * b;
        #pragma unroll
        for (int o = 16; o; o >>= 1) {
            pl += __shfl_xor(pl, o, 32);
            pr += __shfl_xor(pr, o, 32);
        }
        if (lane32 == 0) {
            el1[(row0 + r) * 4 + head] = pl;
            er1[(row0 + r) * 4 + head] = pr;
        }
    }
}

// ---- layer1 pass A: per-edge leaky score -> atomicMax m1[dst,h] ----
__global__ void edge_max1(const int* __restrict__ src, const int* __restrict__ dst,
                          const float* __restrict__ el1, const float* __restrict__ er1,
                          unsigned* __restrict__ m1, int E) {
    int e = blockIdx.x * blockDim.x + threadIdx.x;
    if (e >= E) return;
    int s = src[e], d = dst[e];
    #pragma unroll
    for (int hh = 0; hh < 4; ++hh) {
        float v = el1[s * 4 + hh] + er1[d * 4 + hh];
        v = v > 0.f ? v : NEG_SLOPE * v;
        atomicMax(&m1[d * 4 + hh], encf(v));
    }
}

// ---- layer1 pass B: one wave per edge; ex = exp(e - m); s1 += ex; agg1[d] += ex*z1[s] ----
__global__ __launch_bounds__(256) void edge_agg1(
        const int* __restrict__ src, const int* __restrict__ dst,
        const float* __restrict__ el1, const float* __restrict__ er1,
        const unsigned* __restrict__ m1, const float* __restrict__ z1,
        float* __restrict__ s1, float* __restrict__ agg1, int E) {
    int lane = threadIdx.x & 63;
    int wid = blockIdx.x * (blockDim.x >> 6) + (threadIdx.x >> 6);
    int wstride = gridDim.x * (blockDim.x >> 6);
    for (int e = wid; e < E; e += wstride) {
        int s = src[e], d = dst[e];
        float exv = 0.f;
        if (lane < 4) {
            float v = el1[s * 4 + lane] + er1[d * 4 + lane];
            v = v > 0.f ? v : NEG_SLOPE * v;
            exv = expf(v - decf(m1[d * 4 + lane]));
            unsafeAtomicAdd(&s1[d * 4 + lane], exv);
        }
        float ex0 = __shfl(exv, (lane >> 5), 64);       // head for feature lane
        float ex1 = __shfl(exv, 2 + (lane >> 5), 64);   // head for feature lane+64
        const float* zr = z1 + (size_t)s * 128;
        float* ar = agg1 + (size_t)d * 128;
        unsafeAtomicAdd(&ar[lane],      ex0 * zr[lane]);
        unsafeAtomicAdd(&ar[lane + 64], ex1 * zr[lane + 64]);
    }
}

// ---- finalize layer1 (x = elu(agg/s + b1)) fused with z2 = x@W2, el2/er2 ----
__global__ __launch_bounds__(128) void finalize1_gemm2(
        const float* __restrict__ agg1, const float* __restrict__ s1,
        const float* __restrict__ b1, const float* __restrict__ W2,
        const float* __restrict__ al2, const float* __restrict__ ar2,
        float* __restrict__ z2, float* __restrict__ el2, float* __restrict__ er2) {
    __shared__ float xs[128];
    __shared__ float part[4][32];
    int n = blockIdx.x, tid = threadIdx.x;
    float s = s1[n * 4 + (tid >> 5)];
    float v = agg1[(size_t)n * 128 + tid] / s + b1[tid];
    v = v > 0.f ? v : (expf(v) - 1.f);   // elu
    xs[tid] = v;
    __syncthreads();
    int c = tid & 31, q = tid >> 5;
    float p = 0.f;
    #pragma unroll
    for (int kk = 0; kk < 32; ++kk) {
        int k = q * 32 + kk;
        p += xs[k] * W2[k * 32 + c];
    }
    part[q][c] = p;
    __syncthreads();
    if (tid < 32) {
        float z = part[0][tid] + part[1][tid] + part[2][tid] + part[3][tid];
        z2[(size_t)n * 32 + tid] = z;
        float pl = z * al2[tid], pr = z * ar2[tid];
        #pragma unroll
        for (int o = 16; o; o >>= 1) {
            pl += __shfl_xor(pl, o, 32);
            pr += __shfl_xor(pr, o, 32);
        }
        if (tid == 0) { el2[n] = pl; er2[n] = pr; }
    }
}

// ---- layer2 pass A ----
__global__ void edge_max2(const int* __restrict__ src, const int* __restrict__ dst,
                          const float* __restrict__ el2, const float* __restrict__ er2,
                          unsigned* __restrict__ m2, int E) {
    int e = blockIdx.x * blockDim.x + threadIdx.x;
    if (e >= E) return;
    int d = dst[e];
    float v = el2[src[e]] + er2[d];
    v = v > 0.f ? v : NEG_SLOPE * v;
    atomicMax(&m2[d], encf(v));
}

// ---- layer2 pass B: 32-lane group per edge ----
__global__ __launch_bounds__(256) void edge_agg2(
        const int* __restrict__ src, const int* __restrict__ dst,
        const float* __restrict__ el2, const float* __restrict__ er2,
        const unsigned* __restrict__ m2, const float* __restrict__ z2,
        float* __restrict__ s2, float* __restrict__ agg2, int E) {
    int lane = threadIdx.x & 31;
    int gid = blockIdx.x * (blockDim.x >> 5) + (threadIdx.x >> 5);
    int gstride = gridDim.x * (blockDim.x >> 5);
    for (int e = gid; e < E; e += gstride) {
        int s = src[e], d = dst[e];
        float v = el2[s] + er2[d];
        v = v > 0.f ? v : NEG_SLOPE * v;
        float ex = expf(v - decf(m2[d]));
        if (lane == 0) unsafeAtomicAdd(&s2[d], ex);
        unsafeAtomicAdd(&agg2[(size_t)d * 32 + lane], ex * z2[(size_t)s * 32 + lane]);
    }
}

// ---- final output ----
__global__ void finalize2(const float* __restrict__ agg2, const float* __restrict__ s2,
                          const float* __restrict__ b2, float* __restrict__ out, int N) {
    int i = blockIdx.x * blockDim.x + threadIdx.x;
    if (i >= N * 32) return;
    int n = i >> 5, c = i & 31;
    out[i] = agg2[i] / s2[n] + b2[c];
}

extern "C" void kernel_launch(void* const* d_in, const int* in_sizes, int n_in,
                              void* d_out, int out_size, void* d_ws, size_t ws_size,
                              hipStream_t stream) {
    const float* h   = (const float*)d_in[0];
    const int*   src = (const int*)d_in[1];
    const int*   dst = (const int*)d_in[2];
    const float* W1  = (const float*)d_in[3];
    const float* al1 = (const float*)d_in[4];
    const float* ar1 = (const float*)d_in[5];
    const float* b1  = (const float*)d_in[6];
    const float* W2  = (const float*)d_in[7];
    const float* al2 = (const float*)d_in[8];
    const float* ar2 = (const float*)d_in[9];
    const float* b2  = (const float*)d_in[10];
    float* out = (float*)d_out;
    const int N = NN;
    const int E = in_sizes[1];

    char* w = (char*)d_ws;
    float* z1   = (float*)w; w += (size_t)N * 128 * 4;
    float* agg1 = (float*)w; w += (size_t)N * 128 * 4;
    float* z2   = (float*)w; w += (size_t)N * 32 * 4;
    float* agg2 = (float*)w; w += (size_t)N * 32 * 4;
    float* el1  = (float*)w; w += (size_t)N * 4 * 4;
    float* er1  = (float*)w; w += (size_t)N * 4 * 4;
    float* s1   = (float*)w; w += (size_t)N * 4 * 4;
    unsigned* m1 = (unsigned*)w; w += (size_t)N * 4 * 4;
    float* el2  = (float*)w; w += (size_t)N * 4;
    float* er2  = (float*)w; w += (size_t)N * 4;
    float* s2   = (float*)w; w += (size_t)N * 4;
    unsigned* m2 = (unsigned*)w; w += (size_t)N * 4;

    init_kernel<<<2048, 256, 0, stream>>>(s1, agg1, m1, s2, agg2, m2, N);
    gemm1_kernel<<<N / TM, 128, 0, stream>>>(h, W1, al1, ar1, z1, el1, er1);
    edge_max1<<<(E + 255) / 256, 256, 0, stream>>>(src, dst, el1, er1, m1, E);
    edge_agg1<<<2048, 256, 0, stream>>>(src, dst, el1, er1, m1, z1, s1, agg1, E);
    finalize1_gemm2<<<N, 128, 0, stream>>>(agg1, s1, b1, W2, al2, ar2, z2, el2, er2);
    edge_max2<<<(E + 255) / 256, 256, 0, stream>>>(src, dst, el2, er2, m2, E);
    edge_agg2<<<2048, 256, 0, stream>>>(src, dst, el2, er2, m2, z2, s2, agg2, E);
    finalize2<<<(N * 32 + 255) / 256, 256, 0, stream>>>(agg2, s2, b2, out, N);
}

// Round 2
// 555.081 us; speedup vs baseline: 2.7014x; 2.7014x over previous
//
#include <hip/hip_runtime.h>
#include <hip/hip_bf16.h>

#define NN 50000
#define NEG_SLOPE 0.2f
#define NEG_INF (-1e30f)

// =====================  counting sort of edges by dst  =====================

__global__ void zero_kernel(unsigned* counts, unsigned* cursor, int N) {
    int i = blockIdx.x * blockDim.x + threadIdx.x;
    if (i < N) { counts[i] = 0u; cursor[i] = 0u; }
}

__global__ void hist_kernel(const int* __restrict__ dst, unsigned* __restrict__ counts, int E) {
    int e = blockIdx.x * blockDim.x + threadIdx.x;
    if (e < E) atomicAdd(&counts[dst[e]], 1u);
}

// single-block exclusive scan: off[0..N) = prefix(counts), off[N] = E
__global__ __launch_bounds__(1024) void scan_kernel(const unsigned* __restrict__ counts,
                                                    unsigned* __restrict__ off, int N, int E) {
    __shared__ unsigned wsum[16];
    __shared__ unsigned carry_s;
    int tid = threadIdx.x, lane = tid & 63, w = tid >> 6;
    if (tid == 0) carry_s = 0;
    __syncthreads();
    for (int base = 0; base < N; base += 1024) {
        int i = base + tid;
        unsigned v = (i < N) ? counts[i] : 0u;
        unsigned x = v;
        #pragma unroll
        for (int o = 1; o < 64; o <<= 1) {
            unsigned n = __shfl_up(x, o, 64);
            if (lane >= o) x += n;
        }
        if (lane == 63) wsum[w] = x;
        __syncthreads();
        if (w == 0) {
            unsigned ws_ = (lane < 16) ? wsum[lane] : 0u;
            #pragma unroll
            for (int o = 1; o < 16; o <<= 1) {
                unsigned n = __shfl_up(ws_, o, 64);
                if (lane >= o) ws_ += n;
            }
            if (lane < 16) wsum[lane] = ws_;
        }
        __syncthreads();
        unsigned wpre = (w == 0) ? 0u : wsum[w - 1];
        unsigned carry = carry_s;
        if (i < N) off[i] = carry + wpre + x - v;
        __syncthreads();
        if (tid == 1023) carry_s = carry + wsum[15];
        __syncthreads();
    }
    if (tid == 0) off[N] = (unsigned)E;
}

__global__ void scatter_kernel(const int* __restrict__ src, const int* __restrict__ dst,
                               const unsigned* __restrict__ off, unsigned* __restrict__ cursor,
                               int* __restrict__ src_sorted, int E) {
    int e = blockIdx.x * blockDim.x + threadIdx.x;
    if (e >= E) return;
    int d = dst[e];
    unsigned p = off[d] + atomicAdd(&cursor[d], 1u);
    src_sorted[p] = src[e];
}

// =====================  z1 = h @ W1, fused el1/er1  =====================
#define TM 16
__global__ __launch_bounds__(128) void gemm1_kernel(
        const float* __restrict__ h, const float* __restrict__ W1,
        const float* __restrict__ al1, const float* __restrict__ ar1,
        float* __restrict__ z1, float* __restrict__ el1, float* __restrict__ er1) {
    __shared__ float hs[TM][128];
    int tid = threadIdx.x;
    int row0 = blockIdx.x * TM;
    #pragma unroll
    for (int r = 0; r < TM; ++r)
        hs[r][tid] = h[(size_t)(row0 + r) * 128 + tid];
    __syncthreads();
    float acc[TM];
    #pragma unroll
    for (int r = 0; r < TM; ++r) acc[r] = 0.f;
    for (int k = 0; k < 128; ++k) {
        float w = W1[k * 128 + tid];
        #pragma unroll
        for (int r = 0; r < TM; ++r) acc[r] += hs[r][k] * w;
    }
    float a = al1[tid], b = ar1[tid];
    int head = tid >> 5, lane32 = tid & 31;
    #pragma unroll
    for (int r = 0; r < TM; ++r) {
        z1[(size_t)(row0 + r) * 128 + tid] = acc[r];
        float pl = acc[r] * a, pr = acc[r] * b;
        #pragma unroll
        for (int o = 16; o; o >>= 1) {
            pl += __shfl_xor(pl, o, 32);
            pr += __shfl_xor(pr, o, 32);
        }
        if (lane32 == 0) {
            el1[(row0 + r) * 4 + head] = pl;
            er1[(row0 + r) * 4 + head] = pr;
        }
    }
}

// ============  layer1 aggregate + ELU + gemm2 + el2/er2, one wave/node  ============
__global__ __launch_bounds__(256) void agg1_fused(
        const int* __restrict__ src_sorted, const unsigned* __restrict__ off,
        const float* __restrict__ el1, const float* __restrict__ er1,
        const float* __restrict__ z1, const float* __restrict__ b1,
        const float* __restrict__ W2, const float* __restrict__ al2, const float* __restrict__ ar2,
        float* __restrict__ z2, float* __restrict__ el2, float* __restrict__ er2) {
    __shared__ float W2s[128 * 32];
    __shared__ float xs[4][128];
    int tid = threadIdx.x, lane = tid & 63, w = tid >> 6;
    for (int k = tid; k < 128 * 32; k += 256) W2s[k] = W2[k];

    int node = blockIdx.x * 4 + w;
    int start = (int)off[node], end = (int)off[node + 1];
    const float4* el1v = (const float4*)el1;
    float4 er = ((const float4*)er1)[node];

    // phase 1: per-head max
    float m0 = NEG_INF, m1 = NEG_INF, m2 = NEG_INF, m3 = NEG_INF;
    for (int i = start + lane; i < end; i += 64) {
        float4 el = el1v[src_sorted[i]];
        float v0 = el.x + er.x; v0 = v0 > 0.f ? v0 : NEG_SLOPE * v0;
        float v1 = el.y + er.y; v1 = v1 > 0.f ? v1 : NEG_SLOPE * v1;
        float v2 = el.z + er.z; v2 = v2 > 0.f ? v2 : NEG_SLOPE * v2;
        float v3 = el.w + er.w; v3 = v3 > 0.f ? v3 : NEG_SLOPE * v3;
        m0 = fmaxf(m0, v0); m1 = fmaxf(m1, v1); m2 = fmaxf(m2, v2); m3 = fmaxf(m3, v3);
    }
    #pragma unroll
    for (int o = 32; o; o >>= 1) {
        m0 = fmaxf(m0, __shfl_xor(m0, o, 64));
        m1 = fmaxf(m1, __shfl_xor(m1, o, 64));
        m2 = fmaxf(m2, __shfl_xor(m2, o, 64));
        m3 = fmaxf(m3, __shfl_xor(m3, o, 64));
    }

    // phase 2: ex, sum, message accumulate (lane owns cols lane and lane+64)
    float acc0 = 0.f, acc1 = 0.f;
    float s0 = 0.f, s1 = 0.f, s2 = 0.f, s3 = 0.f;
    for (int base = start; base < end; base += 64) {
        int i = base + lane;
        int s_i = 0;
        float e0 = 0.f, e1 = 0.f, e2 = 0.f, e3 = 0.f;
        if (i < end) {
            s_i = src_sorted[i];
            float4 el = el1v[s_i];
            float v0 = el.x + er.x; v0 = v0 > 0.f ? v0 : NEG_SLOPE * v0;
            float v1 = el.y + er.y; v1 = v1 > 0.f ? v1 : NEG_SLOPE * v1;
            float v2 = el.z + er.z; v2 = v2 > 0.f ? v2 : NEG_SLOPE * v2;
            float v3 = el.w + er.w; v3 = v3 > 0.f ? v3 : NEG_SLOPE * v3;
            e0 = __expf(v0 - m0); e1 = __expf(v1 - m1);
            e2 = __expf(v2 - m2); e3 = __expf(v3 - m3);
            s0 += e0; s1 += e1; s2 += e2; s3 += e3;
        }
        int cnt = min(64, end - base);
        for (int j = 0; j < cnt; ++j) {
            int sj = __shfl(s_i, j, 64);
            float b0 = __shfl(e0, j, 64);
            float b1f = __shfl(e1, j, 64);
            float b2f = __shfl(e2, j, 64);
            float b3f = __shfl(e3, j, 64);
            float exA = (lane < 32) ? b0 : b1f;
            float exB = (lane < 32) ? b2f : b3f;
            const float* zr = z1 + (size_t)sj * 128;
            acc0 += exA * zr[lane];
            acc1 += exB * zr[lane + 64];
        }
    }
    #pragma unroll
    for (int o = 32; o; o >>= 1) {
        s0 += __shfl_xor(s0, o, 64);
        s1 += __shfl_xor(s1, o, 64);
        s2 += __shfl_xor(s2, o, 64);
        s3 += __shfl_xor(s3, o, 64);
    }
    float inv0 = s0 > 0.f ? 1.f / s0 : 0.f;
    float inv1 = s1 > 0.f ? 1.f / s1 : 0.f;
    float inv2 = s2 > 0.f ? 1.f / s2 : 0.f;
    float inv3 = s3 > 0.f ? 1.f / s3 : 0.f;
    float invA = (lane < 32) ? inv0 : inv1;
    float invB = (lane < 32) ? inv2 : inv3;

    float x0 = acc0 * invA + b1[lane];
    float x1 = acc1 * invB + b1[lane + 64];
    x0 = x0 > 0.f ? x0 : (__expf(x0) - 1.f);   // elu
    x1 = x1 > 0.f ? x1 : (__expf(x1) - 1.f);
    xs[w][lane] = x0;
    xs[w][lane + 64] = x1;
    __syncthreads();   // covers W2s staging + xs

    // gemm2: z2[c] = sum_k x[k] * W2[k,32+c]; lane -> (c = lane&31, k-half = lane>>5)
    int c = lane & 31, q = lane >> 5;
    float p = 0.f;
    #pragma unroll 8
    for (int kk = 0; kk < 64; ++kk) {
        int k = q * 64 + kk;
        p += xs[w][k] * W2s[k * 32 + c];
    }
    p += __shfl_xor(p, 32, 64);
    if (lane < 32) {
        z2[(size_t)node * 32 + c] = p;
        float pl = p * al2[c], pr = p * ar2[c];
        #pragma unroll
        for (int o = 16; o; o >>= 1) {
            pl += __shfl_xor(pl, o, 32);
            pr += __shfl_xor(pr, o, 32);
        }
        if (c == 0) { el2[node] = pl; er2[node] = pr; }
    }
}

// ============  layer2 aggregate + output, half-wave per node  ============
__global__ __launch_bounds__(256) void agg2_fused(
        const int* __restrict__ src_sorted, const unsigned* __restrict__ off,
        const float* __restrict__ el2, const float* __restrict__ er2,
        const float* __restrict__ z2, const float* __restrict__ b2,
        float* __restrict__ out) {
    int tid = threadIdx.x;
    int l32 = tid & 31;
    int node = blockIdx.x * 8 + (tid >> 5);
    int start = (int)off[node], end = (int)off[node + 1];
    float er_d = er2[node];

    float m = NEG_INF;
    for (int i = start + l32; i < end; i += 32) {
        float v = el2[src_sorted[i]] + er_d;
        v = v > 0.f ? v : NEG_SLOPE * v;
        m = fmaxf(m, v);
    }
    #pragma unroll
    for (int o = 16; o; o >>= 1) m = fmaxf(m, __shfl_xor(m, o, 32));

    float acc = 0.f, ssum = 0.f;
    for (int base = start; base < end; base += 32) {
        int i = base + l32;
        int s_i = 0;
        float ex = 0.f;
        if (i < end) {
            s_i = src_sorted[i];
            float v = el2[s_i] + er_d;
            v = v > 0.f ? v : NEG_SLOPE * v;
            ex = __expf(v - m);
            ssum += ex;
        }
        int cnt = min(32, end - base);
        for (int j = 0; j < cnt; ++j) {
            int sj = __shfl(s_i, j, 32);
            float exj = __shfl(ex, j, 32);
            acc += exj * z2[(size_t)sj * 32 + l32];
        }
    }
    #pragma unroll
    for (int o = 16; o; o >>= 1) ssum += __shfl_xor(ssum, o, 32);
    float inv = ssum > 0.f ? 1.f / ssum : 0.f;
    out[(size_t)node * 32 + l32] = acc * inv + b2[l32];
}

extern "C" void kernel_launch(void* const* d_in, const int* in_sizes, int n_in,
                              void* d_out, int out_size, void* d_ws, size_t ws_size,
                              hipStream_t stream) {
    const float* h   = (const float*)d_in[0];
    const int*   src = (const int*)d_in[1];
    const int*   dst = (const int*)d_in[2];
    const float* W1  = (const float*)d_in[3];
    const float* al1 = (const float*)d_in[4];
    const float* ar1 = (const float*)d_in[5];
    const float* b1  = (const float*)d_in[6];
    const float* W2  = (const float*)d_in[7];
    const float* al2 = (const float*)d_in[8];
    const float* ar2 = (const float*)d_in[9];
    const float* b2  = (const float*)d_in[10];
    float* out = (float*)d_out;
    const int N = NN;
    const int E = in_sizes[1];

    char* w = (char*)d_ws;
    float* z1         = (float*)w; w += (size_t)N * 128 * 4;
    float* z2         = (float*)w; w += (size_t)N * 32 * 4;
    int*   src_sorted = (int*)w;   w += (size_t)E * 4;
    float* el1        = (float*)w; w += (size_t)N * 4 * 4;
    float* er1        = (float*)w; w += (size_t)N * 4 * 4;
    float* el2        = (float*)w; w += (size_t)N * 4;
    float* er2        = (float*)w; w += (size_t)N * 4;
    unsigned* counts  = (unsigned*)w; w += (size_t)N * 4;
    unsigned* cursor  = (unsigned*)w; w += (size_t)N * 4;
    unsigned* off     = (unsigned*)w; w += (size_t)(N + 16) * 4;

    zero_kernel<<<(N + 255) / 256, 256, 0, stream>>>(counts, cursor, N);
    hist_kernel<<<(E + 255) / 256, 256, 0, stream>>>(dst, counts, E);
    scan_kernel<<<1, 1024, 0, stream>>>(counts, off, N, E);
    scatter_kernel<<<(E + 255) / 256, 256, 0, stream>>>(src, dst, off, cursor, src_sorted, E);
    gemm1_kernel<<<N / TM, 128, 0, stream>>>(h, W1, al1, ar1, z1, el1, er1);
    agg1_fused<<<N / 4, 256, 0, stream>>>(src_sorted, off, el1, er1, z1, b1,
                                          W2, al2, ar2, z2, el2, er2);
    agg2_fused<<<N / 8, 256, 0, stream>>>(src_sorted, off, el2, er2, z2, b2, out);
}

// Round 3
// 434.496 us; speedup vs baseline: 3.4511x; 1.2775x over previous
//
#include <hip/hip_runtime.h>
#include <hip/hip_bf16.h>
#include <hip/hip_fp16.h>

#define NN 50000
#define NEG_SLOPE 0.2f
#define NEG_INF (-1e30f)

// =====================  counting sort of edges by dst  =====================

__global__ void zero_kernel(unsigned* counts, unsigned* cursor, int N) {
    int i = blockIdx.x * blockDim.x + threadIdx.x;
    if (i < N) { counts[i] = 0u; cursor[i] = 0u; }
}

__global__ void hist_kernel(const int* __restrict__ dst, unsigned* __restrict__ counts, int E) {
    int e = blockIdx.x * blockDim.x + threadIdx.x;
    if (e < E) atomicAdd(&counts[dst[e]], 1u);
}

// hierarchical scan: A) per-1024-chunk sums, B) scan chunk sums, C) local scan + add
__global__ __launch_bounds__(256) void scanA(const unsigned* __restrict__ counts,
                                             unsigned* __restrict__ bsum, int N) {
    __shared__ unsigned wls[4];
    int tid = threadIdx.x, lane = tid & 63, wid = tid >> 6;
    int i0 = blockIdx.x * 1024 + tid * 4;
    unsigned t = 0;
    #pragma unroll
    for (int k = 0; k < 4; ++k) if (i0 + k < N) t += counts[i0 + k];
    #pragma unroll
    for (int o = 32; o; o >>= 1) t += __shfl_xor(t, o, 64);
    if (lane == 0) wls[wid] = t;
    __syncthreads();
    if (tid == 0) bsum[blockIdx.x] = wls[0] + wls[1] + wls[2] + wls[3];
}

__global__ void scanB(unsigned* bsum, unsigned* boff, unsigned* off, int nb, int N, int E) {
    int tid = threadIdx.x;  // 64 threads, nb <= 64
    unsigned v = (tid < nb) ? bsum[tid] : 0u;
    unsigned x = v;
    #pragma unroll
    for (int o = 1; o < 64; o <<= 1) {
        unsigned n = __shfl_up(x, o, 64);
        if (tid >= o) x += n;
    }
    if (tid < nb) boff[tid] = x - v;   // exclusive
    if (tid == 0) off[N] = (unsigned)E;
}

__global__ __launch_bounds__(256) void scanC(const unsigned* __restrict__ counts,
                                             const unsigned* __restrict__ boff,
                                             unsigned* __restrict__ off, int N) {
    __shared__ unsigned wls[4];
    int tid = threadIdx.x, lane = tid & 63, wid = tid >> 6;
    int i0 = blockIdx.x * 1024 + tid * 4;
    unsigned c[4];
    #pragma unroll
    for (int k = 0; k < 4; ++k) c[k] = (i0 + k < N) ? counts[i0 + k] : 0u;
    unsigned tsum = c[0] + c[1] + c[2] + c[3];
    unsigned x = tsum;
    #pragma unroll
    for (int o = 1; o < 64; o <<= 1) {
        unsigned n = __shfl_up(x, o, 64);
        if (lane >= o) x += n;
    }
    if (lane == 63) wls[wid] = x;
    __syncthreads();
    if (tid == 0) {
        unsigned r = 0;
        #pragma unroll
        for (int k = 0; k < 4; ++k) { unsigned t = wls[k]; wls[k] = r; r += t; }
    }
    __syncthreads();
    unsigned ex = x - tsum + wls[wid] + boff[blockIdx.x];
    #pragma unroll
    for (int k = 0; k < 4; ++k) {
        if (i0 + k < N) off[i0 + k] = ex;
        ex += c[k];
    }
}

__global__ void scatter_kernel(const int* __restrict__ src, const int* __restrict__ dst,
                               const unsigned* __restrict__ off, unsigned* __restrict__ cursor,
                               int* __restrict__ src_sorted, int E) {
    int e = blockIdx.x * blockDim.x + threadIdx.x;
    if (e >= E) return;
    int d = dst[e];
    unsigned p = off[d] + atomicAdd(&cursor[d], 1u);
    src_sorted[p] = src[e];
}

// =====================  z1 = h @ W1 (fp16 out), fused el1/er1  =====================
#define TM 16
__global__ __launch_bounds__(128) void gemm1_kernel(
        const float* __restrict__ h, const float* __restrict__ W1,
        const float* __restrict__ al1, const float* __restrict__ ar1,
        __half* __restrict__ z1h, float* __restrict__ el1, float* __restrict__ er1) {
    __shared__ float hs[TM][128];
    int tid = threadIdx.x;
    int row0 = blockIdx.x * TM;
    #pragma unroll
    for (int r = 0; r < TM; ++r)
        hs[r][tid] = h[(size_t)(row0 + r) * 128 + tid];
    __syncthreads();
    float acc[TM];
    #pragma unroll
    for (int r = 0; r < TM; ++r) acc[r] = 0.f;
    for (int k = 0; k < 128; ++k) {
        float w = W1[k * 128 + tid];
        #pragma unroll
        for (int r = 0; r < TM; ++r) acc[r] += hs[r][k] * w;
    }
    float a = al1[tid], b = ar1[tid];
    int head = tid >> 5, lane32 = tid & 31;
    #pragma unroll
    for (int r = 0; r < TM; ++r) {
        z1h[(size_t)(row0 + r) * 128 + tid] = __float2half(acc[r]);
        float pl = acc[r] * a, pr = acc[r] * b;
        #pragma unroll
        for (int o = 16; o; o >>= 1) {
            pl += __shfl_xor(pl, o, 32);
            pr += __shfl_xor(pr, o, 32);
        }
        if (lane32 == 0) {
            el1[(row0 + r) * 4 + head] = pl;
            er1[(row0 + r) * 4 + head] = pr;
        }
    }
}

// ======  layer1 alpha: per-edge unnormalized ex[4] + per-node 1/s[4]; wave/node ======
__global__ __launch_bounds__(256) void alpha1_kernel(
        const int* __restrict__ src_sorted, const unsigned* __restrict__ off,
        const float* __restrict__ el1, const float* __restrict__ er1,
        float* __restrict__ alpha1, float* __restrict__ invs1) {
    int lane = threadIdx.x & 63;
    int node = blockIdx.x * 4 + (threadIdx.x >> 6);
    int start = (int)off[node], end = (int)off[node + 1];
    const float4* el1v = (const float4*)el1;
    float4 er = ((const float4*)er1)[node];

    float m0 = NEG_INF, m1 = NEG_INF, m2 = NEG_INF, m3 = NEG_INF;
    for (int i = start + lane; i < end; i += 64) {
        float4 el = el1v[src_sorted[i]];
        float v0 = el.x + er.x; v0 = v0 > 0.f ? v0 : NEG_SLOPE * v0;
        float v1 = el.y + er.y; v1 = v1 > 0.f ? v1 : NEG_SLOPE * v1;
        float v2 = el.z + er.z; v2 = v2 > 0.f ? v2 : NEG_SLOPE * v2;
        float v3 = el.w + er.w; v3 = v3 > 0.f ? v3 : NEG_SLOPE * v3;
        m0 = fmaxf(m0, v0); m1 = fmaxf(m1, v1); m2 = fmaxf(m2, v2); m3 = fmaxf(m3, v3);
    }
    #pragma unroll
    for (int o = 32; o; o >>= 1) {
        m0 = fmaxf(m0, __shfl_xor(m0, o, 64));
        m1 = fmaxf(m1, __shfl_xor(m1, o, 64));
        m2 = fmaxf(m2, __shfl_xor(m2, o, 64));
        m3 = fmaxf(m3, __shfl_xor(m3, o, 64));
    }
    float s0 = 0.f, s1 = 0.f, s2 = 0.f, s3 = 0.f;
    for (int i = start + lane; i < end; i += 64) {
        float4 el = el1v[src_sorted[i]];
        float v0 = el.x + er.x; v0 = v0 > 0.f ? v0 : NEG_SLOPE * v0;
        float v1 = el.y + er.y; v1 = v1 > 0.f ? v1 : NEG_SLOPE * v1;
        float v2 = el.z + er.z; v2 = v2 > 0.f ? v2 : NEG_SLOPE * v2;
        float v3 = el.w + er.w; v3 = v3 > 0.f ? v3 : NEG_SLOPE * v3;
        float e0 = __expf(v0 - m0), e1 = __expf(v1 - m1);
        float e2 = __expf(v2 - m2), e3 = __expf(v3 - m3);
        ((float4*)alpha1)[i] = make_float4(e0, e1, e2, e3);
        s0 += e0; s1 += e1; s2 += e2; s3 += e3;
    }
    #pragma unroll
    for (int o = 32; o; o >>= 1) {
        s0 += __shfl_xor(s0, o, 64);
        s1 += __shfl_xor(s1, o, 64);
        s2 += __shfl_xor(s2, o, 64);
        s3 += __shfl_xor(s3, o, 64);
    }
    if (lane == 0) {
        ((float4*)invs1)[node] = make_float4(
            s0 > 0.f ? 1.f / s0 : 0.f, s1 > 0.f ? 1.f / s1 : 0.f,
            s2 > 0.f ? 1.f / s2 : 0.f, s3 > 0.f ? 1.f / s3 : 0.f);
    }
}

// ====== layer1 SpMM (wave/node, 16-lane group per edge, half8 loads) + elu + gemm2 ======
__global__ __launch_bounds__(256) void agg1_spmm(
        const int* __restrict__ src_sorted, const unsigned* __restrict__ off,
        const __half* __restrict__ z1h, const float* __restrict__ alpha1,
        const float* __restrict__ invs1, const float* __restrict__ b1,
        const float* __restrict__ W2, const float* __restrict__ al2, const float* __restrict__ ar2,
        __half* __restrict__ z2h, float* __restrict__ el2, float* __restrict__ er2) {
    __shared__ float W2s[128 * 32];
    __shared__ float xs[4][128];
    int tid = threadIdx.x, lane = tid & 63, w = tid >> 6;
    for (int k = tid; k < 128 * 32; k += 256) W2s[k] = W2[k];

    int node = blockIdx.x * 4 + w;
    int start = (int)off[node], end = (int)off[node + 1];
    int g = lane >> 4;          // edge slot 0..3
    int l16 = lane & 15;        // cols l16*8 .. +7
    int head = l16 >> 2;

    float acc[8];
    #pragma unroll
    for (int j = 0; j < 8; ++j) acc[j] = 0.f;

    for (int base = start; base < end; base += 8) {
        int i0 = base + g, i1 = base + 4 + g;
        bool v0 = i0 < end, v1 = i1 < end;
        int ic0 = v0 ? i0 : start, ic1 = v1 ? i1 : start;
        int s0 = src_sorted[ic0], s1 = src_sorted[ic1];
        float a0 = v0 ? alpha1[ic0 * 4 + head] : 0.f;
        float a1 = v1 ? alpha1[ic1 * 4 + head] : 0.f;
        float4 r0 = *(const float4*)(z1h + (size_t)s0 * 128 + l16 * 8);
        float4 r1 = *(const float4*)(z1h + (size_t)s1 * 128 + l16 * 8);
        const __half2* h0 = (const __half2*)&r0;
        const __half2* h1 = (const __half2*)&r1;
        #pragma unroll
        for (int k = 0; k < 4; ++k) {
            float2 f0 = __half22float2(h0[k]);
            float2 f1 = __half22float2(h1[k]);
            acc[2 * k]     += a0 * f0.x + a1 * f1.x;
            acc[2 * k + 1] += a0 * f0.y + a1 * f1.y;
        }
    }
    #pragma unroll
    for (int j = 0; j < 8; ++j) {
        acc[j] += __shfl_xor(acc[j], 16, 64);
        acc[j] += __shfl_xor(acc[j], 32, 64);
    }
    if (g == 0) {
        float inv = invs1[node * 4 + head];
        #pragma unroll
        for (int j = 0; j < 8; ++j) {
            float x = acc[j] * inv + b1[l16 * 8 + j];
            x = x > 0.f ? x : (__expf(x) - 1.f);   // elu
            xs[w][l16 * 8 + j] = x;
        }
    }
    __syncthreads();   // covers W2s staging (+ per-wave xs)

    int c = lane & 31, q = lane >> 5;
    float p = 0.f;
    #pragma unroll 8
    for (int kk = 0; kk < 64; ++kk) {
        int k = q * 64 + kk;
        p += xs[w][k] * W2s[k * 32 + c];
    }
    p += __shfl_xor(p, 32, 64);
    if (lane < 32) {
        z2h[(size_t)node * 32 + c] = __float2half(p);
        float pl = p * al2[c], pr = p * ar2[c];
        #pragma unroll
        for (int o = 16; o; o >>= 1) {
            pl += __shfl_xor(pl, o, 32);
            pr += __shfl_xor(pr, o, 32);
        }
        if (c == 0) { el2[node] = pl; er2[node] = pr; }
    }
}

// ======  layer2 alpha: per-edge ex + per-node 1/s; wave/node ======
__global__ __launch_bounds__(256) void alpha2_kernel(
        const int* __restrict__ src_sorted, const unsigned* __restrict__ off,
        const float* __restrict__ el2, const float* __restrict__ er2,
        float* __restrict__ alpha2, float* __restrict__ invs2) {
    int lane = threadIdx.x & 63;
    int node = blockIdx.x * 4 + (threadIdx.x >> 6);
    int start = (int)off[node], end = (int)off[node + 1];
    float er_d = er2[node];

    float m = NEG_INF;
    for (int i = start + lane; i < end; i += 64) {
        float v = el2[src_sorted[i]] + er_d;
        v = v > 0.f ? v : NEG_SLOPE * v;
        m = fmaxf(m, v);
    }
    #pragma unroll
    for (int o = 32; o; o >>= 1) m = fmaxf(m, __shfl_xor(m, o, 64));

    float ssum = 0.f;
    for (int i = start + lane; i < end; i += 64) {
        float v = el2[src_sorted[i]] + er_d;
        v = v > 0.f ? v : NEG_SLOPE * v;
        float ex = __expf(v - m);
        alpha2[i] = ex;
        ssum += ex;
    }
    #pragma unroll
    for (int o = 32; o; o >>= 1) ssum += __shfl_xor(ssum, o, 64);
    if (lane == 0) invs2[node] = ssum > 0.f ? 1.f / ssum : 0.f;
}

// ====== layer2 SpMM (wave/node, 4-lane group per edge, half8 loads) + bias -> out ======
__global__ __launch_bounds__(256) void agg2_spmm(
        const int* __restrict__ src_sorted, const unsigned* __restrict__ off,
        const __half* __restrict__ z2h, const float* __restrict__ alpha2,
        const float* __restrict__ invs2, const float* __restrict__ b2,
        float* __restrict__ out) {
    int lane = threadIdx.x & 63;
    int node = blockIdx.x * 4 + (threadIdx.x >> 6);
    int start = (int)off[node], end = (int)off[node + 1];
    int g = lane >> 2;          // edge slot 0..15
    int l4 = lane & 3;          // cols l4*8 .. +7

    float acc[8];
    #pragma unroll
    for (int j = 0; j < 8; ++j) acc[j] = 0.f;

    for (int base = start; base < end; base += 32) {
        int i0 = base + g, i1 = base + 16 + g;
        bool v0 = i0 < end, v1 = i1 < end;
        int ic0 = v0 ? i0 : start, ic1 = v1 ? i1 : start;
        int s0 = src_sorted[ic0], s1 = src_sorted[ic1];
        float a0 = v0 ? alpha2[ic0] : 0.f;
        float a1 = v1 ? alpha2[ic1] : 0.f;
        float4 r0 = *(const float4*)(z2h + (size_t)s0 * 32 + l4 * 8);
        float4 r1 = *(const float4*)(z2h + (size_t)s1 * 32 + l4 * 8);
        const __half2* h0 = (const __half2*)&r0;
        const __half2* h1 = (const __half2*)&r1;
        #pragma unroll
        for (int k = 0; k < 4; ++k) {
            float2 f0 = __half22float2(h0[k]);
            float2 f1 = __half22float2(h1[k]);
            acc[2 * k]     += a0 * f0.x + a1 * f1.x;
            acc[2 * k + 1] += a0 * f0.y + a1 * f1.y;
        }
    }
    #pragma unroll
    for (int j = 0; j < 8; ++j) {
        acc[j] += __shfl_xor(acc[j], 4, 64);
        acc[j] += __shfl_xor(acc[j], 8, 64);
        acc[j] += __shfl_xor(acc[j], 16, 64);
        acc[j] += __shfl_xor(acc[j], 32, 64);
    }
    if (lane < 4) {
        float inv = invs2[node];
        #pragma unroll
        for (int j = 0; j < 8; ++j)
            out[(size_t)node * 32 + l4 * 8 + j] = acc[j] * inv + b2[l4 * 8 + j];
    }
}

extern "C" void kernel_launch(void* const* d_in, const int* in_sizes, int n_in,
                              void* d_out, int out_size, void* d_ws, size_t ws_size,
                              hipStream_t stream) {
    const float* h   = (const float*)d_in[0];
    const int*   src = (const int*)d_in[1];
    const int*   dst = (const int*)d_in[2];
    const float* W1  = (const float*)d_in[3];
    const float* al1 = (const float*)d_in[4];
    const float* ar1 = (const float*)d_in[5];
    const float* b1  = (const float*)d_in[6];
    const float* W2  = (const float*)d_in[7];
    const float* al2 = (const float*)d_in[8];
    const float* ar2 = (const float*)d_in[9];
    const float* b2  = (const float*)d_in[10];
    float* out = (float*)d_out;
    const int N = NN;
    const int E = in_sizes[1];
    const int NB = (N + 1023) / 1024;   // 49

    char* w = (char*)d_ws;
    __half* z1h       = (__half*)w;   w += (size_t)N * 128 * 2;
    __half* z2h       = (__half*)w;   w += (size_t)N * 32 * 2;
    float* alpha1     = (float*)w;    w += (size_t)E * 4 * 4;
    int*   src_sorted = (int*)w;      w += (size_t)E * 4;
    float* alpha2     = (float*)w;    w += (size_t)E * 4;
    float* el1        = (float*)w;    w += (size_t)N * 4 * 4;
    float* er1        = (float*)w;    w += (size_t)N * 4 * 4;
    float* invs1      = (float*)w;    w += (size_t)N * 4 * 4;
    float* el2        = (float*)w;    w += (size_t)N * 4;
    float* er2        = (float*)w;    w += (size_t)N * 4;
    float* invs2      = (float*)w;    w += (size_t)N * 4;
    unsigned* counts  = (unsigned*)w; w += (size_t)N * 4;
    unsigned* cursor  = (unsigned*)w; w += (size_t)N * 4;
    unsigned* off     = (unsigned*)w; w += (size_t)(N + 16) * 4;
    unsigned* bsum    = (unsigned*)w; w += 64 * 4;
    unsigned* boff    = (unsigned*)w; w += 64 * 4;

    zero_kernel<<<(N + 255) / 256, 256, 0, stream>>>(counts, cursor, N);
    hist_kernel<<<(E + 255) / 256, 256, 0, stream>>>(dst, counts, E);
    scanA<<<NB, 256, 0, stream>>>(counts, bsum, N);
    scanB<<<1, 64, 0, stream>>>(bsum, boff, off, NB, N, E);
    scanC<<<NB, 256, 0, stream>>>(counts, boff, off, N);
    scatter_kernel<<<(E + 255) / 256, 256, 0, stream>>>(src, dst, off, cursor, src_sorted, E);
    gemm1_kernel<<<N / TM, 128, 0, stream>>>(h, W1, al1, ar1, z1h, el1, er1);
    alpha1_kernel<<<N / 4, 256, 0, stream>>>(src_sorted, off, el1, er1, alpha1, invs1);
    agg1_spmm<<<N / 4, 256, 0, stream>>>(src_sorted, off, z1h, alpha1, invs1, b1,
                                         W2, al2, ar2, z2h, el2, er2);
    alpha2_kernel<<<N / 4, 256, 0, stream>>>(src_sorted, off, el2, er2, alpha2, invs2);
    agg2_spmm<<<N / 4, 256, 0, stream>>>(src_sorted, off, z2h, alpha2, invs2, b2, out);
}